// Round 11
// baseline (139.864 us; speedup 1.0000x reference)
//
#include <hip/hip_runtime.h>
#include <math.h>

// ---- problem constants (fixed by reference) ----
#define T_TOK 1024
#define H_DIM 768
#define I_DIM 3072
#define E_NUM 8
#define BM    128
#define BN    64
#define BK    64
#define MSLOTS 16    // max m-tiles at BM=128: 8 + 7 = 15
#define KSPLIT2 4    // FFN2 split-K factor

typedef __attribute__((ext_vector_type(8))) short  short8;   // 8 bf16
typedef __attribute__((ext_vector_type(4))) float  f32x4;

__device__ __forceinline__ unsigned short f2bf(float f) {
  union { float f; unsigned u; } a; a.f = f;
  unsigned r = a.u + 0x7FFFu + ((a.u >> 16) & 1u);  // RTNE
  return (unsigned short)(r >> 16);
}
__device__ __forceinline__ float gelu_exact(float x) {
  return 0.5f * x * (1.0f + erff(x * 0.70710678118654752f));
}
// XOR swizzle: row-major [row][BK] bf16 tile -> conflict-free ds_read_b128 (G4).
__device__ __forceinline__ int swz(int row, int k) {
  return row * BK + (k ^ ((row & 7) << 3));
}
// async global->LDS, 16B per lane. LDS dest = wave-uniform base + lane*16.
__device__ __forceinline__ void gll16(const void* g, void* l) {
  __builtin_amdgcn_global_load_lds(
      (const __attribute__((address_space(1))) void*)g,
      (__attribute__((address_space(3))) void*)l, 16, 0, 0);
}

// ---- kernel 1: deterministic expert routing (ballot rank) + tile list ----
__global__ __launch_bounds__(1024) void route_kernel(
    const int* __restrict__ eidx, int* __restrict__ perm,
    int* __restrict__ tile_e, int* __restrict__ tile_row,
    int* __restrict__ tile_len, int* __restrict__ ntiles) {
  __shared__ int wcnt[16][E_NUM];
  __shared__ int wpre[16][E_NUM];
  __shared__ int offsh[E_NUM + 1];
  const int t = threadIdx.x;        // 1024
  const int lane = t & 63, wave = t >> 6;
  const int e = eidx[t];
  unsigned long long myMask = 0;
#pragma unroll
  for (int ee = 0; ee < E_NUM; ++ee) {
    unsigned long long m = __ballot(e == ee);
    if (ee == e) myMask = m;
    if (lane == 0) wcnt[wave][ee] = __popcll(m);
  }
  const int rank = __popcll(myMask & ((1ull << lane) - 1ull));
  __syncthreads();
  if (t < 16 * E_NUM) {
    const int w = t >> 3, ee = t & 7;
    int p = 0;
    for (int w2 = 0; w2 < w; ++w2) p += wcnt[w2][ee];
    wpre[w][ee] = p;
  }
  __syncthreads();
  if (t <= E_NUM) {
    int off = 0;
    for (int ee = 0; ee < t; ++ee) off += wpre[15][ee] + wcnt[15][ee];
    offsh[t] = off;
  }
  __syncthreads();
  perm[offsh[e] + wpre[wave][e] + rank] = t;
  if (t == 0) {
    int n = 0;
    for (int ee = 0; ee < E_NUM; ++ee)
      for (int r = offsh[ee]; r < offsh[ee + 1]; r += BM) {
        tile_e[n] = ee; tile_row[n] = r;
        tile_len[n] = min(offsh[ee + 1] - r, BM); ++n;
      }
    *ntiles = n;
    for (int i = n; i < MSLOTS; ++i) { tile_e[i] = 0; tile_row[i] = 0; tile_len[i] = 0; }
  }
}

// ---- kernel 2: gather x into perm order, f32 -> bf16 ----
__global__ void gather_kernel(const float* __restrict__ x,
                              const int* __restrict__ perm,
                              unsigned short* __restrict__ xg) {
  const int idx = blockIdx.x * 256 + threadIdx.x;
  if (idx >= T_TOK * (H_DIM / 8)) return;
  const int p = idx / (H_DIM / 8);
  const int c = (idx % (H_DIM / 8)) * 8;
  const int t = perm[p];
  const float* src = x + (size_t)t * H_DIM + c;
  const float4 v0 = *(const float4*)(src);
  const float4 v1 = *(const float4*)(src + 4);
  short8 o;
  o[0] = (short)f2bf(v0.x); o[1] = (short)f2bf(v0.y);
  o[2] = (short)f2bf(v0.z); o[3] = (short)f2bf(v0.w);
  o[4] = (short)f2bf(v1.x); o[5] = (short)f2bf(v1.y);
  o[6] = (short)f2bf(v1.z); o[7] = (short)f2bf(v1.w);
  *(short8*)(xg + (size_t)p * H_DIM + c) = o;
}

// ---- LDS-free weight converter: f32 [E][K][N] -> bf16 tiles
// [E][N/64][K/64][8KB], tile image = GEMM LDS layout (n*64 + (k^((n&7)<<3))).
// Block = (k-octet, expert). Threads = NCOLS/4. Each thread: 8x float4 read
// of FULL rows (perfectly linear, no 4KB-phase pathology), registers only,
// 4x short8 writes (16B aligned). Zero LDS, zero cross-lane.
template <int KROWS, int NCOLS>
__global__ __launch_bounds__(NCOLS / 4) void conv_kernel(
    const float* __restrict__ W, unsigned short* __restrict__ Wt) {
  constexpr int KTT = KROWS / 64, NP = NCOLS / 64;
  const int ko = blockIdx.x;        // k-octet (8 rows)
  const int e  = blockIdx.y;
  const int t  = threadIdx.x;
  const float* src = W + ((size_t)e * KROWS + ko * 8) * NCOLS + t * 4;
  float4 v[8];
#pragma unroll
  for (int j = 0; j < 8; ++j)
    v[j] = *(const float4*)(src + (size_t)j * NCOLS);
  const int k0 = (ko * 8) & 63;
  const int kT = (ko * 8) >> 6;
  const int nb = t * 4;
  const int nT = nb >> 6;
  unsigned short* tile = Wt + ((size_t)(e * NP + nT) * KTT + kT) * 4096;
#pragma unroll
  for (int i = 0; i < 4; ++i) {
    const int nl = (nb + i) & 63;
    short8 o;
#pragma unroll
    for (int j = 0; j < 8; ++j) o[j] = (short)f2bf((&v[j].x)[i]);
    *(short8*)(tile + nl * 64 + (k0 ^ ((nl & 7) << 3))) = o;
  }
}

// ---- grouped GEMM (tiled bf16 weights): BM=128 x BN=64, 8 waves, tri-buf LDS,
// all staging via global_load_lds, 2-deep prefetch, counted vmcnt(3), 1 barrier.
template <int N_FULL, int K_FULL, int KLOOP, bool IS_FFN1>
__global__ __launch_bounds__(512, 4) void moe_gemm_t(
    const unsigned short* __restrict__ A,    // [T_TOK][K_FULL] bf16 (perm order)
    const unsigned short* __restrict__ Wt,   // tiled bf16 weights
    const float* __restrict__ bias,
    const int* __restrict__ tile_e, const int* __restrict__ tile_row,
    const int* __restrict__ tile_len, const int* __restrict__ ntiles,
    unsigned short* __restrict__ out_bf,
    float* __restrict__ part) {
  constexpr int KT  = KLOOP / BK;            // 12
  constexpr int NP  = N_FULL / 64, KTT = K_FULL / 64;
  const int tid  = threadIdx.x;
  const int slot = blockIdx.y;
  if (slot >= *ntiles) return;
  const int e    = tile_e[slot];
  const int row0 = tile_row[slot];
  const int len  = tile_len[slot];
  const int n0   = blockIdx.x * BN;
  const int ktbase = blockIdx.z * KT;

  __shared__ unsigned short As[3][BM * BK];   // 3 x 16 KB
  __shared__ unsigned short Bs[3][BN * BK];   // 3 x  8 KB

  const int lane = tid & 63;
  const int wave = tid >> 6;
  const int wm = wave >> 1, wn = wave & 1;    // 4x2 waves: 32 rows x 32 cols each
  const int lr = lane & 15;
  const int lk = (lane >> 4) * 8;

  // A gll: pre-swizzled global source, linear LDS dest (m173 / r8-proven).
  const unsigned short* agsrc[2];
  int aoff[2];
#pragma unroll
  for (int i = 0; i < 2; ++i) {
    const int c = tid + i * 512;
    const int r = c >> 3, kc = (c & 7) << 3;
    int grow = row0 + r; grow = grow < T_TOK ? grow : (T_TOK - 1);
    agsrc[i] = A + (size_t)grow * K_FULL + ktbase * BK + (kc ^ ((r & 7) << 3));
    aoff[i]  = ((tid & ~63) + i * 512) * 8;   // elems, wave-uniform base
  }
  // B gll: tile image IS the LDS image -> straight 1KB-per-wave copy.
  const unsigned short* btile =
      Wt + ((size_t)(e * NP + blockIdx.x) * KTT + ktbase) * 4096 + wave * 512 + lane * 8;
  const int boff = wave * 512;                 // elems, wave-uniform

  f32x4 acc[2][2] = {};

  auto issue = [&](int t, int b) {
#pragma unroll
    for (int i = 0; i < 2; ++i)
      gll16(agsrc[i] + t * BK, &As[b][aoff[i]]);
    gll16(btile + (size_t)t * 4096, &Bs[b][boff]);
  };
  auto mfma_tile = [&](int b) {
#pragma unroll
    for (int ks = 0; ks < 2; ++ks) {
      const int kpos = ks * 32 + lk;
      short8 af[2], bfr[2];
#pragma unroll
      for (int m = 0; m < 2; ++m)
        af[m] = *(const short8*)(&As[b][swz(wm * 32 + m * 16 + lr, kpos)]);
#pragma unroll
      for (int n = 0; n < 2; ++n)
        bfr[n] = *(const short8*)(&Bs[b][swz(wn * 32 + n * 16 + lr, kpos)]);
#pragma unroll
      for (int m = 0; m < 2; ++m)
#pragma unroll
        for (int n = 0; n < 2; ++n)
          acc[m][n] = __builtin_amdgcn_mfma_f32_16x16x32_bf16(af[m], bfr[n], acc[m][n], 0, 0, 0);
    }
  };

  issue(0, 0);
  issue(1, 1);
#pragma unroll 1
  for (int t = 0; t < KT; ++t) {
    const int b = t % 3;                      // LDS base math only (no reg array)
    // entry outstanding (per wave): tile t (3 instrs) + tile t+1 (3 instrs)
    if (t == KT - 1) asm volatile("s_waitcnt vmcnt(0)" ::: "memory");
    else             asm volatile("s_waitcnt vmcnt(3)" ::: "memory");
    __builtin_amdgcn_s_barrier();             // all waves: tile t landed
    __builtin_amdgcn_sched_barrier(0);
    if (t + 2 < KT) issue(t + 2, (t + 2) % 3);
    __builtin_amdgcn_sched_barrier(0);
    mfma_tile(b);
  }

  // epilogue: C/D layout col=lane&15, row=(lane>>4)*4+j  [verified m89]
#pragma unroll
  for (int n = 0; n < 2; ++n) {
    const int gc = n0 + wn * 32 + n * 16 + lr;
    float bv = 0.f;
    if constexpr (IS_FFN1) bv = bias[(size_t)e * N_FULL + gc];
#pragma unroll
    for (int m = 0; m < 2; ++m) {
      const int rbase = wm * 32 + m * 16 + (lane >> 4) * 4;
#pragma unroll
      for (int j = 0; j < 4; ++j) {
        const int rl = rbase + j;
        if (rl < len) {
          if constexpr (IS_FFN1) {
            out_bf[(size_t)(row0 + rl) * N_FULL + gc] = f2bf(gelu_exact(acc[m][n][j] + bv));
          } else {
            part[((size_t)blockIdx.z * T_TOK + row0 + rl) * N_FULL + gc] = acc[m][n][j];
          }
        }
      }
    }
  }
}

// ---- fallback grouped GEMM reading f32 weights directly (r8, proven) ----
template <int N_FULL, int K_FULL, int KLOOP, bool IS_FFN1>
__global__ __launch_bounds__(512, 4) void moe_gemm_f(
    const unsigned short* __restrict__ A,
    const float* __restrict__ W,
    const float* __restrict__ bias,
    const int* __restrict__ tile_e, const int* __restrict__ tile_row,
    const int* __restrict__ tile_len, const int* __restrict__ ntiles,
    unsigned short* __restrict__ out_bf,
    float* __restrict__ part) {
  constexpr int KT = KLOOP / BK;
  const int tid  = threadIdx.x;
  const int slot = blockIdx.y;
  if (slot >= *ntiles) return;
  const int e    = tile_e[slot];
  const int row0 = tile_row[slot];
  const int len  = tile_len[slot];
  const int n0   = blockIdx.x * BN;
  const int kbase = blockIdx.z * KLOOP;
  const float* We = W + (size_t)e * K_FULL * N_FULL;
  __shared__ unsigned short As[2][BM * BK];
  __shared__ unsigned short Bs[2][BN * BK];
  const int lane = tid & 63;
  const int wave = tid >> 6;
  const int wm = wave >> 1, wn = wave & 1;
  const int lr = lane & 15;
  const int lk = (lane >> 4) * 8;
  const unsigned short* agsrc[2];
  int aoff[2];
#pragma unroll
  for (int i = 0; i < 2; ++i) {
    const int c = tid + i * 512;
    const int r = c >> 3, kc = (c & 7) << 3;
    int grow = row0 + r; grow = grow < T_TOK ? grow : (T_TOK - 1);
    agsrc[i] = A + (size_t)grow * K_FULL + kbase + (kc ^ ((r & 7) << 3));
    aoff[i]  = ((tid & ~63) + i * 512) * 8;
  }
  const int bn_ = tid & 63;
  const int kb8 = (tid >> 6) * 8;
  const float* wpB = We + (size_t)(kbase + kb8) * N_FULL + n0 + bn_;
  f32x4 acc[2][2] = {};
  float X[8], Y[8];
  auto issueA = [&](int kt, int buf) {
#pragma unroll
    for (int i = 0; i < 2; ++i)
      gll16(agsrc[i] + kt * BK, &As[buf][aoff[i]]);
  };
  auto loadB = [&](int kt, float* d) {
#pragma unroll
    for (int j = 0; j < 8; ++j)
      d[j] = wpB[(size_t)(kt * BK + j) * N_FULL];
  };
  auto writeB = [&](int buf, const float* d) {
    short8 p;
#pragma unroll
    for (int j = 0; j < 8; ++j) p[j] = (short)f2bf(d[j]);
    *(short8*)(&Bs[buf][swz(bn_, kb8)]) = p;
  };
  auto mfma_tile = [&](int buf) {
#pragma unroll
    for (int ks = 0; ks < 2; ++ks) {
      const int kp = ks * 32 + lk;
      short8 af[2], bfr[2];
#pragma unroll
      for (int m = 0; m < 2; ++m)
        af[m] = *(const short8*)(&As[buf][swz(wm * 32 + m * 16 + lr, kp)]);
#pragma unroll
      for (int n = 0; n < 2; ++n)
        bfr[n] = *(const short8*)(&Bs[buf][swz(wn * 32 + n * 16 + lr, kp)]);
#pragma unroll
      for (int m = 0; m < 2; ++m)
#pragma unroll
        for (int n = 0; n < 2; ++n)
          acc[m][n] = __builtin_amdgcn_mfma_f32_16x16x32_bf16(af[m], bfr[n], acc[m][n], 0, 0, 0);
    }
  };
  auto phase = [&](int t, int buf, float* setCur, bool nextA, bool nextB, bool drain) {
    if (drain) asm volatile("s_waitcnt vmcnt(0)" ::: "memory");
    else       asm volatile("s_waitcnt vmcnt(8)" ::: "memory");
    writeB(buf, setCur);
    asm volatile("s_waitcnt lgkmcnt(0)" ::: "memory");
    __builtin_amdgcn_s_barrier();
    __builtin_amdgcn_sched_barrier(0);
    if (nextA) issueA(t + 1, buf ^ 1);
    __builtin_amdgcn_sched_barrier(0);
    if (nextB) loadB(t + 2, setCur);
    __builtin_amdgcn_sched_barrier(0);
    mfma_tile(buf);
  };
  loadB(0, X);
  __builtin_amdgcn_sched_barrier(0);
  issueA(0, 0);
  __builtin_amdgcn_sched_barrier(0);
  loadB(1, Y);
#pragma unroll 1
  for (int t = 0; t < KT - 2; t += 2) {
    phase(t,     0, X, true, true, false);
    phase(t + 1, 1, Y, true, true, false);
  }
  phase(KT - 2, 0, X, true,  false, false);
  phase(KT - 1, 1, Y, false, false, true);
#pragma unroll
  for (int n = 0; n < 2; ++n) {
    const int gc = n0 + wn * 32 + n * 16 + lr;
    float bv = 0.f;
    if constexpr (IS_FFN1) bv = bias[(size_t)e * N_FULL + gc];
#pragma unroll
    for (int m = 0; m < 2; ++m) {
      const int rbase = wm * 32 + m * 16 + (lane >> 4) * 4;
#pragma unroll
      for (int j = 0; j < 4; ++j) {
        const int rl = rbase + j;
        if (rl < len) {
          if constexpr (IS_FFN1) {
            out_bf[(size_t)(row0 + rl) * N_FULL + gc] = f2bf(gelu_exact(acc[m][n][j] + bv));
          } else {
            part[((size_t)blockIdx.z * T_TOK + row0 + rl) * N_FULL + gc] = acc[m][n][j];
          }
        }
      }
    }
  }
}

// ---- kernel 5: split-K sum + bias2 + residual + LayerNorm ----
__global__ void ln_kernel(const float* __restrict__ part,
                          const float* __restrict__ x,
                          const int* __restrict__ perm,
                          const int* __restrict__ eidx,
                          const float* __restrict__ b2,
                          const float* __restrict__ gamma,
                          const float* __restrict__ beta,
                          float* __restrict__ out) {
  const int p = blockIdx.x;
  const int tid = threadIdx.x;  // 256
  const int t = perm[p];
  const int e = eidx[t];
  float v[3], s = 0.f, ss = 0.f;
#pragma unroll
  for (int i = 0; i < 3; ++i) {
    const int c = tid + i * 256;
    float a = x[(size_t)t * H_DIM + c] + b2[(size_t)e * H_DIM + c];
#pragma unroll
    for (int s4 = 0; s4 < KSPLIT2; ++s4)
      a += part[((size_t)s4 * T_TOK + p) * H_DIM + c];
    v[i] = a; s += a; ss += a * a;
  }
#pragma unroll
  for (int o = 32; o; o >>= 1) { s += __shfl_down(s, o); ss += __shfl_down(ss, o); }
  __shared__ float ps[4], pss[4];
  __shared__ float mu_s, ir_s;
  const int w = tid >> 6;
  if ((tid & 63) == 0) { ps[w] = s; pss[w] = ss; }
  __syncthreads();
  if (tid == 0) {
    const float S = ps[0] + ps[1] + ps[2] + ps[3];
    const float SS = pss[0] + pss[1] + pss[2] + pss[3];
    const float mu = S * (1.0f / H_DIM);
    const float var = SS * (1.0f / H_DIM) - mu * mu;
    mu_s = mu; ir_s = rsqrtf(var + 1e-12f);
  }
  __syncthreads();
  const float mu = mu_s, ir = ir_s;
#pragma unroll
  for (int i = 0; i < 3; ++i) {
    const int c = tid + i * 256;
    out[(size_t)t * H_DIM + c] = (v[i] - mu) * ir * gamma[c] + beta[c];
  }
}

extern "C" void kernel_launch(void* const* d_in, const int* in_sizes, int n_in,
                              void* d_out, int out_size, void* d_ws, size_t ws_size,
                              hipStream_t stream) {
  const float* x     = (const float*)d_in[0];
  const int*   eidx  = (const int*)d_in[1];
  const float* W1    = (const float*)d_in[2];
  const float* b1    = (const float*)d_in[3];
  const float* W2    = (const float*)d_in[4];
  const float* b2    = (const float*)d_in[5];
  const float* gamma = (const float*)d_in[6];
  const float* beta  = (const float*)d_in[7];
  float* out = (float*)d_out;

  char* ws = (char*)d_ws;
  int* perm     = (int*)(ws);
  int* tile_e   = (int*)(ws + 4096);
  int* tile_row = (int*)(ws + 4352);
  int* tile_len = (int*)(ws + 4608);
  int* ntiles   = (int*)(ws + 4864);
  size_t off = 8192;
  unsigned short* xg = (unsigned short*)(ws + off);    off += (size_t)2 * T_TOK * H_DIM;
  unsigned short* inter = (unsigned short*)(ws + off); off += (size_t)2 * T_TOK * I_DIM;
  float* part = (float*)(ws + off);                    off += (size_t)4 * KSPLIT2 * T_TOK * H_DIM;
  unsigned short* w1t = (unsigned short*)(ws + off);   off += (size_t)2 * E_NUM * H_DIM * I_DIM;
  unsigned short* w2t = (unsigned short*)(ws + off);
  const size_t need = off + (size_t)2 * E_NUM * H_DIM * I_DIM;   // ~91.5 MB
  const bool tiled = ws_size >= need;

  route_kernel<<<1, T_TOK, 0, stream>>>(eidx, perm, tile_e, tile_row, tile_len, ntiles);
  gather_kernel<<<(T_TOK * (H_DIM / 8) + 255) / 256, 256, 0, stream>>>(x, perm, xg);
  if (tiled) {
    // conv1 -> gemm1 -> conv2 -> gemm2: each GEMM reads its tile array L3-hot.
    conv_kernel<H_DIM, I_DIM><<<dim3(H_DIM / 8, E_NUM), I_DIM / 4, 0, stream>>>(W1, w1t);
    moe_gemm_t<I_DIM, H_DIM, H_DIM, true>
        <<<dim3(I_DIM / BN, MSLOTS, 1), 512, 0, stream>>>(
        xg, w1t, b1, tile_e, tile_row, tile_len, ntiles, inter, nullptr);
    conv_kernel<I_DIM, H_DIM><<<dim3(I_DIM / 8, E_NUM), H_DIM / 4, 0, stream>>>(W2, w2t);
    moe_gemm_t<H_DIM, I_DIM, I_DIM / KSPLIT2, false>
        <<<dim3(H_DIM / BN, MSLOTS, KSPLIT2), 512, 0, stream>>>(
        inter, w2t, nullptr, tile_e, tile_row, tile_len, ntiles, nullptr, part);
  } else {
    moe_gemm_f<I_DIM, H_DIM, H_DIM, true>
        <<<dim3(I_DIM / BN, MSLOTS, 1), 512, 0, stream>>>(
        xg, W1, b1, tile_e, tile_row, tile_len, ntiles, inter, nullptr);
    moe_gemm_f<H_DIM, I_DIM, I_DIM / KSPLIT2, false>
        <<<dim3(H_DIM / BN, MSLOTS, KSPLIT2), 512, 0, stream>>>(
        inter, W2, nullptr, tile_e, tile_row, tile_len, ntiles, nullptr, part);
  }
  ln_kernel<<<T_TOK, 256, 0, stream>>>(part, x, perm, eidx, b2, gamma, beta, out);
  (void)in_sizes; (void)n_in; (void)out_size;
}

// Round 12
// 88.370 us; speedup vs baseline: 1.5827x; 1.5827x over previous
//
#include <hip/hip_runtime.h>
#include <math.h>

// ---- problem constants (fixed by reference) ----
#define T_TOK 1024
#define H_DIM 768
#define I_DIM 3072
#define E_NUM 8
#define BM    128
#define BN    64
#define BK    64
#define MSLOTS 16    // max m-tiles at BM=128: 8 + 7 = 15
#define KSPLIT2 4    // FFN2 split-K factor
#define CONV_Y 8     // converter slots appended to FFN1 grid.y
#define NCONVB (48 * CONV_Y)                        // 384 converter blocks
#define CONV_CHUNKS (E_NUM * I_DIM * H_DIM / 8)     // 2359296 8-elem chunks
#define CONV_PER_T (CONV_CHUNKS / (NCONVB * 512))   // 12

typedef __attribute__((ext_vector_type(8))) short  short8;   // 8 bf16
typedef __attribute__((ext_vector_type(4))) float  f32x4;

__device__ __forceinline__ unsigned short f2bf(float f) {
  union { float f; unsigned u; } a; a.f = f;
  unsigned r = a.u + 0x7FFFu + ((a.u >> 16) & 1u);  // RTNE
  return (unsigned short)(r >> 16);
}
__device__ __forceinline__ float gelu_exact(float x) {
  return 0.5f * x * (1.0f + erff(x * 0.70710678118654752f));
}
// XOR swizzle: row-major [row][BK] bf16 tile -> conflict-free ds_read_b128 (G4).
__device__ __forceinline__ int swz(int row, int k) {
  return row * BK + (k ^ ((row & 7) << 3));
}
// async global->LDS, 16B per lane. LDS dest = wave-uniform base + lane*16.
__device__ __forceinline__ void gll16(const void* g, void* l) {
  __builtin_amdgcn_global_load_lds(
      (const __attribute__((address_space(1))) void*)g,
      (__attribute__((address_space(3))) void*)l, 16, 0, 0);
}

// ---- kernel 1: deterministic expert routing (ballot rank) + tile list ----
__global__ __launch_bounds__(1024) void route_kernel(
    const int* __restrict__ eidx, int* __restrict__ perm,
    int* __restrict__ tile_e, int* __restrict__ tile_row,
    int* __restrict__ tile_len, int* __restrict__ ntiles) {
  __shared__ int wcnt[16][E_NUM];
  __shared__ int wpre[16][E_NUM];
  __shared__ int offsh[E_NUM + 1];
  const int t = threadIdx.x;        // 1024
  const int lane = t & 63, wave = t >> 6;
  const int e = eidx[t];
  unsigned long long myMask = 0;
#pragma unroll
  for (int ee = 0; ee < E_NUM; ++ee) {
    unsigned long long m = __ballot(e == ee);
    if (ee == e) myMask = m;
    if (lane == 0) wcnt[wave][ee] = __popcll(m);
  }
  const int rank = __popcll(myMask & ((1ull << lane) - 1ull));
  __syncthreads();
  if (t < 16 * E_NUM) {
    const int w = t >> 3, ee = t & 7;
    int p = 0;
    for (int w2 = 0; w2 < w; ++w2) p += wcnt[w2][ee];
    wpre[w][ee] = p;
  }
  __syncthreads();
  if (t <= E_NUM) {
    int off = 0;
    for (int ee = 0; ee < t; ++ee) off += wpre[15][ee] + wcnt[15][ee];
    offsh[t] = off;
  }
  __syncthreads();
  perm[offsh[e] + wpre[wave][e] + rank] = t;
  if (t == 0) {
    int n = 0;
    for (int ee = 0; ee < E_NUM; ++ee)
      for (int r = offsh[ee]; r < offsh[ee + 1]; r += BM) {
        tile_e[n] = ee; tile_row[n] = r;
        tile_len[n] = min(offsh[ee + 1] - r, BM); ++n;
      }
    *ntiles = n;
    for (int i = n; i < MSLOTS; ++i) { tile_e[i] = 0; tile_row[i] = 0; tile_len[i] = 0; }
  }
}

// ---- kernel 2: gather x into perm order, f32 -> bf16 ----
__global__ void gather_kernel(const float* __restrict__ x,
                              const int* __restrict__ perm,
                              unsigned short* __restrict__ xg) {
  const int idx = blockIdx.x * 256 + threadIdx.x;
  if (idx >= T_TOK * (H_DIM / 8)) return;
  const int p = idx / (H_DIM / 8);
  const int c = (idx % (H_DIM / 8)) * 8;
  const int t = perm[p];
  const float* src = x + (size_t)t * H_DIM + c;
  const float4 v0 = *(const float4*)(src);
  const float4 v1 = *(const float4*)(src + 4);
  short8 o;
  o[0] = (short)f2bf(v0.x); o[1] = (short)f2bf(v0.y);
  o[2] = (short)f2bf(v0.z); o[3] = (short)f2bf(v0.w);
  o[4] = (short)f2bf(v1.x); o[5] = (short)f2bf(v1.y);
  o[6] = (short)f2bf(v1.z); o[7] = (short)f2bf(v1.w);
  *(short8*)(xg + (size_t)p * H_DIM + c) = o;
}

// ---- standalone f32 -> bf16 converter, NATURAL layout (linear in, linear out)
__global__ __launch_bounds__(512) void cvt_kernel(
    const float* __restrict__ src, unsigned short* __restrict__ dst) {
  const int idx = blockIdx.x * 512 + threadIdx.x;   // one short8 chunk
  if (idx >= CONV_CHUNKS) return;
  const float4 a = ((const float4*)src)[2 * idx];
  const float4 b = ((const float4*)src)[2 * idx + 1];
  short8 o;
  o[0] = (short)f2bf(a.x); o[1] = (short)f2bf(a.y);
  o[2] = (short)f2bf(a.z); o[3] = (short)f2bf(a.w);
  o[4] = (short)f2bf(b.x); o[5] = (short)f2bf(b.y);
  o[6] = (short)f2bf(b.z); o[7] = (short)f2bf(b.w);
  ((short8*)dst)[idx] = o;
}

// ---- grouped GEMM, BM=128 x BN=64, 8 waves (4x2, 32x32 each), dbuf LDS ----
// r8 counted-vmcnt pipeline, B read as bf16 u16 (natural layout, L3-hot).
// A via global_load_lds (pre-swizzled source, linear dest, m173).
// IS_FFN1 && B_BF16: grid.y slots >= MSLOTS run the overlapped W2 converter
// (linear read, linear write — r6-proven fusion).
template <int N_FULL, int K_FULL, int KLOOP, bool IS_FFN1, bool B_BF16>
__global__ __launch_bounds__(512, 4) void moe_gemm(
    const unsigned short* __restrict__ A,   // [T_TOK][K_FULL] bf16 (perm order)
    const void* __restrict__ Wv,            // [E][K_FULL][N_FULL] f32 or bf16
    const float* __restrict__ bias,         // [E][N_FULL] (FFN1 only)
    const int* __restrict__ tile_e, const int* __restrict__ tile_row,
    const int* __restrict__ tile_len, const int* __restrict__ ntiles,
    unsigned short* __restrict__ out_bf,    // FFN1 out
    float* __restrict__ part,               // FFN2 partials [KSPLIT2][T_TOK][N_FULL]
    const float* __restrict__ convSrc,      // W2 f32 (FFN1 only)
    unsigned short* __restrict__ convDst) { // w2b
  constexpr int KT = KLOOP / BK;            // 12 (even)
  const int tid  = threadIdx.x;
  const int slot = blockIdx.y;

  if constexpr (IS_FFN1 && B_BF16) {
    if (slot >= MSLOTS) {                   // overlapped W2 f32->bf16 stream
      const int cb  = blockIdx.x + 48 * (slot - MSLOTS);
      const int lin = cb * 512 + tid;
      const float4* s4 = (const float4*)convSrc;
      short8* d8 = (short8*)convDst;
#pragma unroll
      for (int j = 0; j < CONV_PER_T; ++j) {
        const int idx = j * (NCONVB * 512) + lin;
        const float4 a = s4[2 * idx], b = s4[2 * idx + 1];
        short8 o;
        o[0] = (short)f2bf(a.x); o[1] = (short)f2bf(a.y);
        o[2] = (short)f2bf(a.z); o[3] = (short)f2bf(a.w);
        o[4] = (short)f2bf(b.x); o[5] = (short)f2bf(b.y);
        o[6] = (short)f2bf(b.z); o[7] = (short)f2bf(b.w);
        d8[idx] = o;
      }
      return;
    }
  }
  if (slot >= *ntiles) return;
  const int e    = tile_e[slot];
  const int row0 = tile_row[slot];
  const int len  = tile_len[slot];
  const int n0   = blockIdx.x * BN;
  const int kbase = blockIdx.z * KLOOP;

  __shared__ unsigned short As[2][BM * BK];   // 2 x 16 KB, linear chunk order
  __shared__ unsigned short Bs[2][BN * BK];   // 2 x  8 KB, [n][k] swizzled

  const int lane = tid & 63;
  const int wave = tid >> 6;
  const int wm = wave >> 1, wn = wave & 1;    // 4x2 waves: 32 rows x 32 cols each
  const int lr = lane & 15;
  const int lk = (lane >> 4) * 8;

  // A gll addressing: pre-swizzled source, linear LDS dest (m173 / r8-proven).
  const unsigned short* agsrc[2];
  int aoff[2];
#pragma unroll
  for (int i = 0; i < 2; ++i) {
    const int c = tid + i * 512;
    const int r = c >> 3, kc = (c & 7) << 3;
    int grow = row0 + r; grow = grow < T_TOK ? grow : (T_TOK - 1);
    agsrc[i] = A + (size_t)grow * K_FULL + kbase + (kc ^ ((r & 7) << 3));
    aoff[i]  = ((tid & ~63) + i * 512) * 8;   // wave-uniform 16B-chunk base
  }
  // B staging: lane = column (coalesced), wave owns 8 k-rows. f32 or u16.
  const int bn_ = tid & 63;                   // col
  const int kb8 = (tid >> 6) * 8;             // row block
  const float* wpF = nullptr; const unsigned short* wpH = nullptr;
  if constexpr (B_BF16)
    wpH = (const unsigned short*)Wv + (size_t)e * K_FULL * N_FULL +
          (size_t)(kbase + kb8) * N_FULL + n0 + bn_;
  else
    wpF = (const float*)Wv + (size_t)e * K_FULL * N_FULL +
          (size_t)(kbase + kb8) * N_FULL + n0 + bn_;

  f32x4 acc[2][2] = {};
  float Xf[8], Yf[8];
  unsigned short Xh[8], Yh[8];

  auto issueA = [&](int kt, int buf) {
#pragma unroll
    for (int i = 0; i < 2; ++i)
      gll16(agsrc[i] + kt * BK, &As[buf][aoff[i]]);
  };
  auto loadB = [&](int kt, float* df, unsigned short* dh) {
#pragma unroll
    for (int j = 0; j < 8; ++j) {
      if constexpr (B_BF16) dh[j] = wpH[(size_t)(kt * BK + j) * N_FULL];
      else                  df[j] = wpF[(size_t)(kt * BK + j) * N_FULL];
    }
  };
  auto writeB = [&](int buf, const float* df, const unsigned short* dh) {
    short8 p;
#pragma unroll
    for (int j = 0; j < 8; ++j)
      p[j] = B_BF16 ? (short)dh[j] : (short)f2bf(df[j]);
    *(short8*)(&Bs[buf][swz(bn_, kb8)]) = p;        // one b128 (r8: 0 conflicts)
  };
  auto mfma_tile = [&](int buf) {
#pragma unroll
    for (int ks = 0; ks < 2; ++ks) {
      const int kp = ks * 32 + lk;
      short8 af[2], bfr[2];
#pragma unroll
      for (int m = 0; m < 2; ++m)
        af[m] = *(const short8*)(&As[buf][swz(wm * 32 + m * 16 + lr, kp)]);
#pragma unroll
      for (int n = 0; n < 2; ++n)
        bfr[n] = *(const short8*)(&Bs[buf][swz(wn * 32 + n * 16 + lr, kp)]);
#pragma unroll
      for (int m = 0; m < 2; ++m)
#pragma unroll
        for (int n = 0; n < 2; ++n)
          acc[m][n] = __builtin_amdgcn_mfma_f32_16x16x32_bf16(af[m], bfr[n], acc[m][n], 0, 0, 0);
    }
  };
  // phase t entry queue (oldest->newest): B(t) x8, A(t) x2, B(t+1) x8.
  // vmcnt(8) drains B(t)+A(t), keeps B(t+1) in flight across the barrier.
  auto phase = [&](int t, int buf, float* cf, unsigned short* ch,
                   bool nextA, bool nextB, bool drain) {
    if (drain) asm volatile("s_waitcnt vmcnt(0)" ::: "memory");
    else       asm volatile("s_waitcnt vmcnt(8)" ::: "memory");
    writeB(buf, cf, ch);
    asm volatile("s_waitcnt lgkmcnt(0)" ::: "memory");
    __builtin_amdgcn_s_barrier();
    __builtin_amdgcn_sched_barrier(0);
    if (nextA) issueA(t + 1, buf ^ 1);
    __builtin_amdgcn_sched_barrier(0);
    if (nextB) loadB(t + 2, cf, ch);     // reuses the set just written to LDS
    __builtin_amdgcn_sched_barrier(0);
    mfma_tile(buf);
  };

  loadB(0, Xf, Xh);
  __builtin_amdgcn_sched_barrier(0);
  issueA(0, 0);
  __builtin_amdgcn_sched_barrier(0);
  loadB(1, Yf, Yh);
#pragma unroll 1
  for (int t = 0; t < KT - 2; t += 2) {
    phase(t,     0, Xf, Xh, true, true, false);
    phase(t + 1, 1, Yf, Yh, true, true, false);
  }
  phase(KT - 2, 0, Xf, Xh, true,  false, false);
  phase(KT - 1, 1, Yf, Yh, false, false, true);

  // epilogue: C/D layout col=lane&15, row=(lane>>4)*4+j  [verified m89]
#pragma unroll
  for (int n = 0; n < 2; ++n) {
    const int gc = n0 + wn * 32 + n * 16 + lr;
    float bv = 0.f;
    if constexpr (IS_FFN1) bv = bias[(size_t)e * N_FULL + gc];
#pragma unroll
    for (int m = 0; m < 2; ++m) {
      const int rbase = wm * 32 + m * 16 + (lane >> 4) * 4;
#pragma unroll
      for (int j = 0; j < 4; ++j) {
        const int rl = rbase + j;
        if (rl < len) {
          if constexpr (IS_FFN1) {
            out_bf[(size_t)(row0 + rl) * N_FULL + gc] = f2bf(gelu_exact(acc[m][n][j] + bv));
          } else {
            part[((size_t)blockIdx.z * T_TOK + row0 + rl) * N_FULL + gc] = acc[m][n][j];
          }
        }
      }
    }
  }
}

// ---- kernel 5: split-K sum + bias2 + residual + LayerNorm ----
__global__ void ln_kernel(const float* __restrict__ part,
                          const float* __restrict__ x,
                          const int* __restrict__ perm,
                          const int* __restrict__ eidx,
                          const float* __restrict__ b2,
                          const float* __restrict__ gamma,
                          const float* __restrict__ beta,
                          float* __restrict__ out) {
  const int p = blockIdx.x;
  const int tid = threadIdx.x;  // 256
  const int t = perm[p];
  const int e = eidx[t];
  float v[3], s = 0.f, ss = 0.f;
#pragma unroll
  for (int i = 0; i < 3; ++i) {
    const int c = tid + i * 256;
    float a = x[(size_t)t * H_DIM + c] + b2[(size_t)e * H_DIM + c];
#pragma unroll
    for (int s4 = 0; s4 < KSPLIT2; ++s4)
      a += part[((size_t)s4 * T_TOK + p) * H_DIM + c];
    v[i] = a; s += a; ss += a * a;
  }
#pragma unroll
  for (int o = 32; o; o >>= 1) { s += __shfl_down(s, o); ss += __shfl_down(ss, o); }
  __shared__ float ps[4], pss[4];
  __shared__ float mu_s, ir_s;
  const int w = tid >> 6;
  if ((tid & 63) == 0) { ps[w] = s; pss[w] = ss; }
  __syncthreads();
  if (tid == 0) {
    const float S = ps[0] + ps[1] + ps[2] + ps[3];
    const float SS = pss[0] + pss[1] + pss[2] + pss[3];
    const float mu = S * (1.0f / H_DIM);
    const float var = SS * (1.0f / H_DIM) - mu * mu;
    mu_s = mu; ir_s = rsqrtf(var + 1e-12f);
  }
  __syncthreads();
  const float mu = mu_s, ir = ir_s;
#pragma unroll
  for (int i = 0; i < 3; ++i) {
    const int c = tid + i * 256;
    out[(size_t)t * H_DIM + c] = (v[i] - mu) * ir * gamma[c] + beta[c];
  }
}

extern "C" void kernel_launch(void* const* d_in, const int* in_sizes, int n_in,
                              void* d_out, int out_size, void* d_ws, size_t ws_size,
                              hipStream_t stream) {
  const float* x     = (const float*)d_in[0];
  const int*   eidx  = (const int*)d_in[1];
  const float* W1    = (const float*)d_in[2];
  const float* b1    = (const float*)d_in[3];
  const float* W2    = (const float*)d_in[4];
  const float* b2    = (const float*)d_in[5];
  const float* gamma = (const float*)d_in[6];
  const float* beta  = (const float*)d_in[7];
  float* out = (float*)d_out;

  char* ws = (char*)d_ws;
  int* perm     = (int*)(ws);
  int* tile_e   = (int*)(ws + 4096);
  int* tile_row = (int*)(ws + 4352);
  int* tile_len = (int*)(ws + 4608);
  int* ntiles   = (int*)(ws + 4864);
  size_t off = 8192;
  unsigned short* xg = (unsigned short*)(ws + off);    off += (size_t)2 * T_TOK * H_DIM;
  unsigned short* inter = (unsigned short*)(ws + off); off += (size_t)2 * T_TOK * I_DIM;
  float* part = (float*)(ws + off);                    off += (size_t)4 * KSPLIT2 * T_TOK * H_DIM;
  unsigned short* w1b = (unsigned short*)(ws + off);   off += (size_t)2 * E_NUM * H_DIM * I_DIM;
  unsigned short* w2b = (unsigned short*)(ws + off);
  const size_t need = off + (size_t)2 * E_NUM * H_DIM * I_DIM;   // ~95.95 MB (= r10's, fits)
  const bool bf = ws_size >= need;

  route_kernel<<<1, T_TOK, 0, stream>>>(eidx, perm, tile_e, tile_row, tile_len, ntiles);
  gather_kernel<<<(T_TOK * (H_DIM / 8) + 255) / 256, 256, 0, stream>>>(x, perm, xg);
  if (bf) {
    // W1 -> bf16 (linear in, linear out, no transpose)
    cvt_kernel<<<(CONV_CHUNKS + 511) / 512, 512, 0, stream>>>(W1, w1b);
    // FFN1 (bf16 W1, L3-hot) + fused W2 converter in extra grid.y slots
    moe_gemm<I_DIM, H_DIM, H_DIM, true, true>
        <<<dim3(I_DIM / BN, MSLOTS + CONV_Y, 1), 512, 0, stream>>>(
        xg, w1b, b1, tile_e, tile_row, tile_len, ntiles, inter, nullptr, W2, w2b);
    // FFN2 (bf16 W2, L3-hot)
    moe_gemm<H_DIM, I_DIM, I_DIM / KSPLIT2, false, true>
        <<<dim3(H_DIM / BN, MSLOTS, KSPLIT2), 512, 0, stream>>>(
        inter, w2b, nullptr, tile_e, tile_row, tile_len, ntiles, nullptr, part,
        nullptr, nullptr);
  } else {
    moe_gemm<I_DIM, H_DIM, H_DIM, true, false>
        <<<dim3(I_DIM / BN, MSLOTS, 1), 512, 0, stream>>>(
        xg, W1, b1, tile_e, tile_row, tile_len, ntiles, inter, nullptr,
        nullptr, nullptr);
    moe_gemm<H_DIM, I_DIM, I_DIM / KSPLIT2, false, false>
        <<<dim3(H_DIM / BN, MSLOTS, KSPLIT2), 512, 0, stream>>>(
        inter, W2, nullptr, tile_e, tile_row, tile_len, ntiles, nullptr, part,
        nullptr, nullptr);
  }
  ln_kernel<<<T_TOK, 256, 0, stream>>>(part, x, perm, eidx, b2, gamma, beta, out);
  (void)in_sizes; (void)n_in; (void)out_size;
}